// Round 5
// baseline (1377.652 us; speedup 1.0000x reference)
//
#include <hip/hip_runtime.h>

// GLA (gated linear attention) forward scan, fp32.
// q,k,v,g: [B=2, H=16, T=4096, D=128] fp32.  out = (o [B,H,T,D], h_final [B,H,D,D]).
//
// Strategy: per-(b,h) the state h[128,128] is a diagonal linear recurrence
// h_t = h_{t-1} * exp(g_t)[:,None] + k_t v_t^T ; columns (Dv) are independent.
// Segmented scan over T: S=32 segments of 128 steps.
//   k1: eg = exp(g) (precompute, removes transcendentals from hot loops) and
//       A[bh,seg,kappa] = exp(sum of g over segment).
//   k2: per-segment contribution C_seg = scan from h=0 (no output).
//   k3: sequential combine over segments (tiny) -> per-seg initial states
//       (in-place over C) + h_final to d_out.
//   k4: per-segment re-scan from true initial state, producing o.
// Layout: block = 128 threads (2 waves) = one (bh,seg); lane owns one state
// COLUMN (all 128 k) in 128 VGPRs. exp(g)/k/q are wave-uniform broadcast
// loads (L1), v and o are coalesced per-lane. No LDS, no shuffles.

#define BHN 32
#define TT 4096
#define DDIM 128
#define NSEG 32
#define TSEG 128  // TT / NSEG
#define GLA_SCALE 0.08838834764831845f  // 1/sqrt(128)

__device__ __forceinline__ float4 ldu4(const float* p) {
  return *reinterpret_cast<const float4*>(p);
}

// ---- k1: eg = exp(g); A[bh,seg,kk] = exp(sum_t g) ----
__global__ void k1_gate(const float* __restrict__ g, float* __restrict__ eg,
                        float* __restrict__ A) {
  const int bh = blockIdx.x / NSEG;
  const int seg = blockIdx.x % NSEG;
  const int kk = threadIdx.x;  // 0..127 (key index)
  const size_t base = ((size_t)bh * TT + (size_t)seg * TSEG) * DDIM + kk;
  const float* gp = g + base;
  float* ep = eg + base;
  float sum = 0.f;
#pragma unroll 4
  for (int t = 0; t < TSEG; ++t) {
    float gv = gp[(size_t)t * DDIM];
    sum += gv;
    ep[(size_t)t * DDIM] = expf(gv);
  }
  A[((size_t)bh * NSEG + seg) * DDIM + kk] = expf(sum);
}

// ---- k2: per-segment state contribution (scan from zero, no output) ----
__global__ __launch_bounds__(128, 2) void k2_contrib(
    const float* __restrict__ kten, const float* __restrict__ vten,
    const float* __restrict__ eg, float* __restrict__ hC) {
  const int bh = blockIdx.x / NSEG;
  const int seg = blockIdx.x % NSEG;
  const int nu = threadIdx.x;  // value-dim column this lane owns
  float h[DDIM];
#pragma unroll
  for (int i = 0; i < DDIM; ++i) h[i] = 0.f;
  const size_t base = ((size_t)bh * TT + (size_t)seg * TSEG) * DDIM;
  for (int t = 0; t < TSEG; ++t) {
    const float* ep = eg + base + (size_t)t * DDIM;
    const float* kp = kten + base + (size_t)t * DDIM;
    const float vv = vten[base + (size_t)t * DDIM + nu];
#pragma unroll
    for (int c = 0; c < DDIM / 4; ++c) {
      float4 e4 = ldu4(ep + 4 * c);  // wave-uniform broadcast
      float4 k4 = ldu4(kp + 4 * c);
      h[4 * c + 0] = fmaf(h[4 * c + 0], e4.x, k4.x * vv);
      h[4 * c + 1] = fmaf(h[4 * c + 1], e4.y, k4.y * vv);
      h[4 * c + 2] = fmaf(h[4 * c + 2], e4.z, k4.z * vv);
      h[4 * c + 3] = fmaf(h[4 * c + 3], e4.w, k4.w * vv);
    }
  }
  // write C[bh,seg,kappa,nu]; coalesced across nu
  float* out = hC + ((size_t)bh * NSEG + seg) * (DDIM * DDIM) + nu;
#pragma unroll
  for (int i = 0; i < DDIM; ++i) out[(size_t)i * DDIM] = h[i];
}

// ---- k3: combine segments sequentially (in place: C[s] -> h_init[s]) ----
__global__ void k3_combine(float* __restrict__ hC, const float* __restrict__ A,
                           float* __restrict__ hfinal) {
  const size_t idx = (size_t)blockIdx.x * 256 + threadIdx.x;  // over BH*D*D
  const int bh = (int)(idx >> 14);
  const int kk = (int)((idx >> 7) & 127);
  const size_t knu = idx & 16383;  // (kappa,nu) within a state
  float h = 0.f;
  for (int s = 0; s < NSEG; ++s) {
    const size_t off = ((size_t)bh * NSEG + s) * 16384 + knu;
    const float c = hC[off];
    hC[off] = h;  // initial state for segment s
    h = fmaf(h, A[((size_t)bh * NSEG + s) * DDIM + kk], c);
  }
  hfinal[(size_t)bh * 16384 + knu] = h;
}

// ---- k4: re-scan each segment from its true initial state, emit o ----
__global__ __launch_bounds__(128, 2) void k4_out(
    const float* __restrict__ qten, const float* __restrict__ kten,
    const float* __restrict__ vten, const float* __restrict__ eg,
    const float* __restrict__ h0, float* __restrict__ o) {
  const int bh = blockIdx.x / NSEG;
  const int seg = blockIdx.x % NSEG;
  const int nu = threadIdx.x;
  float h[DDIM];
  const float* hi = h0 + ((size_t)bh * NSEG + seg) * (DDIM * DDIM) + nu;
#pragma unroll
  for (int i = 0; i < DDIM; ++i) h[i] = hi[(size_t)i * DDIM];
  const size_t base = ((size_t)bh * TT + (size_t)seg * TSEG) * DDIM;
  for (int t = 0; t < TSEG; ++t) {
    const float* ep = eg + base + (size_t)t * DDIM;
    const float* kp = kten + base + (size_t)t * DDIM;
    const float* qp = qten + base + (size_t)t * DDIM;
    const float vv = vten[base + (size_t)t * DDIM + nu];
    float a0 = 0.f, a1 = 0.f, a2 = 0.f, a3 = 0.f;  // 4 acc chains for ILP
#pragma unroll
    for (int c = 0; c < DDIM / 4; ++c) {
      float4 e4 = ldu4(ep + 4 * c);  // wave-uniform broadcast loads
      float4 k4 = ldu4(kp + 4 * c);
      float4 q4 = ldu4(qp + 4 * c);
      float t0 = fmaf(h[4 * c + 0], e4.x, k4.x * vv);
      h[4 * c + 0] = t0;
      a0 = fmaf(q4.x, t0, a0);
      float t1 = fmaf(h[4 * c + 1], e4.y, k4.y * vv);
      h[4 * c + 1] = t1;
      a1 = fmaf(q4.y, t1, a1);
      float t2 = fmaf(h[4 * c + 2], e4.z, k4.z * vv);
      h[4 * c + 2] = t2;
      a2 = fmaf(q4.z, t2, a2);
      float t3 = fmaf(h[4 * c + 3], e4.w, k4.w * vv);
      h[4 * c + 3] = t3;
      a3 = fmaf(q4.w, t3, a3);
    }
    o[base + (size_t)t * DDIM + nu] = ((a0 + a1) + (a2 + a3)) * GLA_SCALE;
  }
}

extern "C" void kernel_launch(void* const* d_in, const int* in_sizes, int n_in,
                              void* d_out, int out_size, void* d_ws,
                              size_t ws_size, hipStream_t stream) {
  const float* q = (const float*)d_in[0];
  const float* k = (const float*)d_in[1];
  const float* v = (const float*)d_in[2];
  const float* g = (const float*)d_in[3];

  float* o = (float*)d_out;                      // [BH, T, D]
  float* hfinal = o + (size_t)BHN * TT * DDIM;   // [BH, D, D]

  // workspace layout (fp32): eg[BH*T*D] | C/h_init[BH*NSEG*D*D] | A[BH*NSEG*D]
  // total = (16777216 + 16777216 + 131072) * 4B = ~134.7 MB
  float* ws = (float*)d_ws;
  float* eg = ws;
  float* hC = ws + (size_t)BHN * TT * DDIM;
  float* A = hC + (size_t)BHN * NSEG * DDIM * DDIM;

  k1_gate<<<BHN * NSEG, 128, 0, stream>>>(g, eg, A);
  k2_contrib<<<BHN * NSEG, 128, 0, stream>>>(k, v, eg, hC);
  k3_combine<<<(BHN * DDIM * DDIM) / 256, 256, 0, stream>>>(hC, A, hfinal);
  k4_out<<<BHN * NSEG, 128, 0, stream>>>(q, k, v, eg, hC, o);
}